// Round 3
// baseline (94.477 us; speedup 1.0000x reference)
//
#include <hip/hip_runtime.h>

#define HH 512
#define WW 512
#define HWPIX (HH * WW)
#define BPB 64            // blocks per batch
#define NB  32            // batches
#define NBLK (BPB * NB)   // 2048 blocks total
#define NT  256

struct Partial {
    int   pa, va;          // plaque / vessel counts
    float pc, vc;          // conf-weighted sums
    int   rmin, rmax, cmin, cmax;  // plaque bbox
};

__device__ __forceinline__ void waveReduce(int& pa, int& va, float& pc, float& vc,
                                           int& rmin, int& rmax, int& cmin, int& cmax) {
    #pragma unroll
    for (int off = 32; off > 0; off >>= 1) {
        pa += __shfl_down(pa, off, 64);
        va += __shfl_down(va, off, 64);
        pc += __shfl_down(pc, off, 64);
        vc += __shfl_down(vc, off, 64);
        rmin = min(rmin, __shfl_down(rmin, off, 64));
        rmax = max(rmax, __shfl_down(rmax, off, 64));
        cmin = min(cmin, __shfl_down(cmin, off, 64));
        cmax = max(cmax, __shfl_down(cmax, off, 64));
    }
}

__global__ __launch_bounds__(NT)
void mfe_fused(const float* __restrict__ in, Partial* __restrict__ part,
               unsigned* __restrict__ counter, float* __restrict__ out) {
    const int b = blockIdx.y, k = blockIdx.x, tid = threadIdx.x;

    const float4* p0 = (const float4*)(in + (size_t)b * 3 * HWPIX);
    const float4* p1 = p0 + (HWPIX / 4);
    const float4* p2 = p0 + (HWPIX / 2);

    int   pa = 0, va = 0;
    float pc = 0.f, vc = 0.f;
    int   rmin = HH, rmax = -1, cmin = WW, cmax = -1;

    // 8 pixels (2 float4 per channel stream) per iteration, 2 iterations.
    #pragma unroll 1
    for (int it = 0; it < 2; ++it) {
        const int g2 = it * (BPB * NT) + k * NT + tid;   // double-group in [0, 32768)
        const int g  = g2 * 2;
        float4 a0 = p0[g], a1 = p0[g + 1];
        float4 b0 = p1[g], b1 = p1[g + 1];
        float4 c0 = p2[g], c1 = p2[g + 1];
        const int row     = g2 >> 6;          // 8 px per group, 512 px per row
        const int colbase = (g2 & 63) << 3;
        unsigned pmask = 0u;
        const float* A0 = (const float*)&a0; const float* A1 = (const float*)&a1;
        const float* B0 = (const float*)&b0; const float* B1 = (const float*)&b1;
        const float* C0 = (const float*)&c0; const float* C1 = (const float*)&c1;
        #pragma unroll
        for (int j = 0; j < 8; ++j) {
            float l0 = (j < 4) ? A0[j] : A1[j - 4];
            float l1 = (j < 4) ? B0[j] : B1[j - 4];
            float l2 = (j < 4) ? C0[j] : C1[j - 4];
            float m01 = fmaxf(l0, l1);
            float m   = fmaxf(m01, l2);
            float s   = __expf(l0 - m) + __expf(l1 - m) + __expf(l2 - m);
            float conf = 1.0f / s;                 // softmax prob of argmax channel
            bool isV = l2 > m01;                   // pred==2 (first-index argmax)
            bool isP = (l1 > l0) && !isV;          // pred==1
            pa += isP; va += isV;
            pc += isP ? conf : 0.f;
            vc += isV ? conf : 0.f;
            pmask |= (unsigned)isP << j;
        }
        if (pmask) {
            rmin = min(rmin, row);
            rmax = max(rmax, row);
            cmin = min(cmin, colbase + (__ffs(pmask) - 1));
            cmax = max(cmax, colbase + (31 - __clz(pmask)));
        }
    }

    waveReduce(pa, va, pc, vc, rmin, rmax, cmin, cmax);

    __shared__ Partial sp[NT / 64];
    __shared__ int lastFlag;
    const int lane = tid & 63, wid = tid >> 6;
    if (lane == 0) sp[wid] = Partial{pa, va, pc, vc, rmin, rmax, cmin, cmax};
    __syncthreads();

    if (tid == 0) {
        Partial r = sp[0];
        #pragma unroll
        for (int w = 1; w < NT / 64; ++w) {
            r.pa += sp[w].pa;  r.va += sp[w].va;
            r.pc += sp[w].pc;  r.vc += sp[w].vc;
            r.rmin = min(r.rmin, sp[w].rmin);
            r.rmax = max(r.rmax, sp[w].rmax);
            r.cmin = min(r.cmin, sp[w].cmin);
            r.cmax = max(r.cmax, sp[w].cmax);
        }
        part[b * BPB + k] = r;
        __threadfence();                          // release partial (device scope)
        unsigned old = atomicAdd(counter, 1u);    // device-scope RMW
        lastFlag = (old == NBLK - 1);
    }
    __syncthreads();
    if (!lastFlag) return;
    __threadfence();                              // acquire all partials

    // Last block: 4 waves x 8 batches; lane i reduces partial i of the batch.
    #pragma unroll 1
    for (int i = 0; i < 8; ++i) {
        const int bb = wid * 8 + i;
        Partial r = part[bb * BPB + lane];
        int pa2 = r.pa, va2 = r.va;
        float pc2 = r.pc, vc2 = r.vc;
        int rmin2 = r.rmin, rmax2 = r.rmax, cmin2 = r.cmin, cmax2 = r.cmax;
        waveReduce(pa2, va2, pc2, vc2, rmin2, rmax2, cmin2, cmax2);
        if (lane == 0) {
            const float paf = (float)pa2;
            const float vaf = (float)va2;
            const float fa  = paf + vaf;                  // fg = plaque + vessel
            const bool  ne  = (rmax2 >= 0);
            const float hr  = ne ? (float)(rmax2 - rmin2) : 0.f;
            const float wr  = ne ? (float)(cmax2 - cmin2) : 0.f;
            float* o = out + bb * 10;
            o[0] = paf / (vaf + 1e-6f);
            o[1] = paf / (fa + 1e-6f);
            o[2] = pc2;
            o[3] = hr / (float)HH;
            o[4] = wr / (float)WW;
            o[5] = 2.0f * (hr + wr) / (float)(HH + WW);
            o[6] = vc2;
            o[7] = (pa2 > 0) ? (pc2 / (paf + 1e-6f)) : 0.f;
            o[8] = fa / (float)HWPIX;
            o[9] = paf / (float)HWPIX;
        }
    }
}

extern "C" void kernel_launch(void* const* d_in, const int* in_sizes, int n_in,
                              void* d_out, int out_size, void* d_ws, size_t ws_size,
                              hipStream_t stream) {
    const float* in  = (const float*)d_in[0];
    float*       out = (float*)d_out;
    Partial*     part = (Partial*)d_ws;
    unsigned*    counter = (unsigned*)((char*)d_ws + NBLK * sizeof(Partial));

    // ws is poisoned (0xAA) before timing and never re-poisoned between replays:
    // zero the completion counter every call (graph-capturable async memset).
    hipMemsetAsync(counter, 0, sizeof(unsigned), stream);

    dim3 grid(BPB, NB);
    mfe_fused<<<grid, NT, 0, stream>>>(in, part, counter, out);
}

// Round 4
// 24.693 us; speedup vs baseline: 3.8260x; 3.8260x over previous
//
#include <hip/hip_runtime.h>

#define HH 512
#define WW 512
#define HWPIX (HH * WW)
#define BPB 64            // blocks per batch
#define NB  32            // batches
#define NT  256

struct Partial {
    int   pa, va;          // plaque / vessel counts
    float pc, vc;          // conf-weighted sums
    int   rmin, rmax, cmin, cmax;  // plaque bbox
};

__device__ __forceinline__ void waveReduce(int& pa, int& va, float& pc, float& vc,
                                           int& rmin, int& rmax, int& cmin, int& cmax) {
    #pragma unroll
    for (int off = 32; off > 0; off >>= 1) {
        pa += __shfl_down(pa, off, 64);
        va += __shfl_down(va, off, 64);
        pc += __shfl_down(pc, off, 64);
        vc += __shfl_down(vc, off, 64);
        rmin = min(rmin, __shfl_down(rmin, off, 64));
        rmax = max(rmax, __shfl_down(rmax, off, 64));
        cmin = min(cmin, __shfl_down(cmin, off, 64));
        cmax = max(cmax, __shfl_down(cmax, off, 64));
    }
}

__global__ __launch_bounds__(NT)
void mfe_reduce(const float* __restrict__ in, Partial* __restrict__ part) {
    const int b = blockIdx.y, k = blockIdx.x, tid = threadIdx.x;

    const float4* p0 = (const float4*)(in + (size_t)b * 3 * HWPIX);
    const float4* p1 = p0 + (HWPIX / 4);
    const float4* p2 = p0 + (HWPIX / 2);

    // Issue ALL 12 16B loads up front (192 B/thread in flight) for MLP.
    const int g2_0 = 0 * (BPB * NT) + k * NT + tid;  // double-group id, iter 0
    const int g2_1 = 1 * (BPB * NT) + k * NT + tid;  // double-group id, iter 1
    const int g0 = g2_0 * 2, g1 = g2_1 * 2;
    float4 a00 = p0[g0], a01 = p0[g0 + 1];
    float4 b00 = p1[g0], b01 = p1[g0 + 1];
    float4 c00 = p2[g0], c01 = p2[g0 + 1];
    float4 a10 = p0[g1], a11 = p0[g1 + 1];
    float4 b10 = p1[g1], b11 = p1[g1 + 1];
    float4 c10 = p2[g1], c11 = p2[g1 + 1];

    int   pa = 0, va = 0;
    float pc = 0.f, vc = 0.f;
    int   rmin = HH, rmax = -1, cmin = WW, cmax = -1;

    const float* A[4] = {(const float*)&a00, (const float*)&a01, (const float*)&a10, (const float*)&a11};
    const float* Bp[4] = {(const float*)&b00, (const float*)&b01, (const float*)&b10, (const float*)&b11};
    const float* Cp[4] = {(const float*)&c00, (const float*)&c01, (const float*)&c10, (const float*)&c11};

    #pragma unroll
    for (int half = 0; half < 2; ++half) {
        const int g2 = half ? g2_1 : g2_0;
        const int row     = g2 >> 6;          // 8 px per double-group, 512 px/row
        const int colbase = (g2 & 63) << 3;
        unsigned pmask = 0u;
        #pragma unroll
        for (int j = 0; j < 8; ++j) {
            const int q = half * 2 + (j >> 2), e = j & 3;
            float l0 = A[q][e];
            float l1 = Bp[q][e];
            float l2 = Cp[q][e];
            float m01 = fmaxf(l0, l1);
            float m   = fmaxf(m01, l2);
            float s   = __expf(l0 - m) + __expf(l1 - m) + __expf(l2 - m);
            float conf = 1.0f / s;                 // softmax prob of argmax channel
            bool isV = l2 > m01;                   // pred==2 (first-index argmax)
            bool isP = (l1 > l0) && !isV;          // pred==1
            pa += isP; va += isV;
            pc += isP ? conf : 0.f;
            vc += isV ? conf : 0.f;
            pmask |= (unsigned)isP << j;
        }
        if (pmask) {
            rmin = min(rmin, row);
            rmax = max(rmax, row);
            cmin = min(cmin, colbase + (__ffs(pmask) - 1));
            cmax = max(cmax, colbase + (31 - __clz(pmask)));
        }
    }

    waveReduce(pa, va, pc, vc, rmin, rmax, cmin, cmax);

    __shared__ Partial sp[NT / 64];
    const int lane = tid & 63, wid = tid >> 6;
    if (lane == 0) sp[wid] = Partial{pa, va, pc, vc, rmin, rmax, cmin, cmax};
    __syncthreads();
    if (tid == 0) {
        Partial r = sp[0];
        #pragma unroll
        for (int w = 1; w < NT / 64; ++w) {
            r.pa += sp[w].pa;  r.va += sp[w].va;
            r.pc += sp[w].pc;  r.vc += sp[w].vc;
            r.rmin = min(r.rmin, sp[w].rmin);
            r.rmax = max(r.rmax, sp[w].rmax);
            r.cmin = min(r.cmin, sp[w].cmin);
            r.cmax = max(r.cmax, sp[w].cmax);
        }
        part[b * BPB + k] = r;
    }
}

__global__ __launch_bounds__(64)
void mfe_finalize(const Partial* __restrict__ part, float* __restrict__ out) {
    const int b    = blockIdx.x;
    const int lane = threadIdx.x;
    Partial r = part[b * BPB + lane];
    int pa = r.pa, va = r.va;
    float pc = r.pc, vc = r.vc;
    int rmin = r.rmin, rmax = r.rmax, cmin = r.cmin, cmax = r.cmax;

    waveReduce(pa, va, pc, vc, rmin, rmax, cmin, cmax);

    if (lane == 0) {
        const float paf = (float)pa;
        const float vaf = (float)va;
        const float fa  = paf + vaf;                  // fg = plaque + vessel
        const bool  ne  = (rmax >= 0);
        const float hr  = ne ? (float)(rmax - rmin) : 0.f;
        const float wr  = ne ? (float)(cmax - cmin) : 0.f;
        float* o = out + b * 10;
        o[0] = paf / (vaf + 1e-6f);
        o[1] = paf / (fa + 1e-6f);
        o[2] = pc;
        o[3] = hr / (float)HH;
        o[4] = wr / (float)WW;
        o[5] = 2.0f * (hr + wr) / (float)(HH + WW);
        o[6] = vc;
        o[7] = (pa > 0) ? (pc / (paf + 1e-6f)) : 0.f;
        o[8] = fa / (float)HWPIX;
        o[9] = paf / (float)HWPIX;
    }
}

extern "C" void kernel_launch(void* const* d_in, const int* in_sizes, int n_in,
                              void* d_out, int out_size, void* d_ws, size_t ws_size,
                              hipStream_t stream) {
    const float* in  = (const float*)d_in[0];
    float*       out = (float*)d_out;
    Partial*     part = (Partial*)d_ws;

    dim3 grid(BPB, NB);
    mfe_reduce<<<grid, NT, 0, stream>>>(in, part);
    mfe_finalize<<<NB, 64, 0, stream>>>(part, out);
}

// Round 5
// 24.429 us; speedup vs baseline: 3.8674x; 1.0108x over previous
//
#include <hip/hip_runtime.h>

#define HH 512
#define WW 512
#define HWPIX (HH * WW)
#define BPB 64            // blocks per batch
#define NB  32            // batches
#define NT  256
#define ITERS 4           // float4-groups per thread

struct Partial {
    int   pa, va;          // plaque / vessel counts
    float pc, vc;          // conf-weighted sums
    int   rmin, rmax, cmin, cmax;  // plaque bbox
};

__global__ __launch_bounds__(NT)
void mfe_reduce(const float* __restrict__ in, Partial* __restrict__ part) {
    const int b = blockIdx.y, k = blockIdx.x, tid = threadIdx.x;

    const float4* p0 = (const float4*)(in + (size_t)b * 3 * HWPIX);
    const float4* p1 = p0 + (HWPIX / 4);
    const float4* p2 = p0 + (HWPIX / 2);

    int   cnt = 0;                 // pa | va<<16 (max 16/thread, 4096/block)
    float pc = 0.f, vc = 0.f;
    int   rmin = HH, rmax = -1, cmin = WW, cmax = -1;

    // g: float4 index; consecutive lanes -> consecutive float4 (1KB/instr, coalesced)
    int g = k * NT + tid;
    float4 a = p0[g], b4 = p1[g], c4 = p2[g];

    #pragma unroll
    for (int i = 0; i < ITERS; ++i) {
        const int gn = g + BPB * NT;
        float4 a_n, b_n, c_n;
        if (i < ITERS - 1) { a_n = p0[gn]; b_n = p1[gn]; c_n = p2[gn]; }

        const int row     = g >> 7;          // 128 float4 per 512-px row
        const int colbase = (g & 127) << 2;
        unsigned msk = 0u;
        const float* A = (const float*)&a;
        const float* B = (const float*)&b4;
        const float* C = (const float*)&c4;
        #pragma unroll
        for (int j = 0; j < 4; ++j) {
            float l0 = A[j], l1 = B[j], l2 = C[j];
            float m01 = fmaxf(l0, l1);
            float m   = fmaxf(m01, l2);
            float t0 = l0 - m, t1 = l1 - m, t2 = l2 - m;   // t_max == 0
            float tmin = fminf(fminf(t0, t1), t2);          // v_min3
            float tmid = ((t0 + t1) + t2) - tmin;           // mid = sum - min (max=0)
            float s    = 1.0f + __expf(tmid) + __expf(tmin);
            float conf = __builtin_amdgcn_rcpf(s);          // softmax prob of argmax
            bool isV = l2 > m01;                            // pred==2, first-index rule
            bool isP = (l1 > l0) && !isV;                   // pred==1
            cnt += (int)isP | ((int)isV << 16);
            pc  += isP ? conf : 0.f;
            vc  += isV ? conf : 0.f;
            msk |= (unsigned)isP << j;
        }
        if (msk) {
            rmin = min(rmin, row);
            rmax = max(rmax, row);
            cmin = min(cmin, colbase + (__ffs(msk) - 1));
            cmax = max(cmax, colbase + (31 - __clz(msk)));
        }
        a = a_n; b4 = b_n; c4 = c_n; g = gn;
    }

    // wave (64-lane) shuffle reduce: 7 channels
    #pragma unroll
    for (int off = 32; off > 0; off >>= 1) {
        cnt += __shfl_down(cnt, off, 64);
        pc  += __shfl_down(pc, off, 64);
        vc  += __shfl_down(vc, off, 64);
        rmin = min(rmin, __shfl_down(rmin, off, 64));
        rmax = max(rmax, __shfl_down(rmax, off, 64));
        cmin = min(cmin, __shfl_down(cmin, off, 64));
        cmax = max(cmax, __shfl_down(cmax, off, 64));
    }

    struct SPart { int cnt; float pc, vc; int rmin, rmax, cmin, cmax; };
    __shared__ SPart sp[NT / 64];
    const int lane = tid & 63, wid = tid >> 6;
    if (lane == 0) sp[wid] = SPart{cnt, pc, vc, rmin, rmax, cmin, cmax};
    __syncthreads();
    if (tid == 0) {
        SPart r = sp[0];
        #pragma unroll
        for (int w = 1; w < NT / 64; ++w) {
            r.cnt += sp[w].cnt;
            r.pc  += sp[w].pc;   r.vc += sp[w].vc;
            r.rmin = min(r.rmin, sp[w].rmin);
            r.rmax = max(r.rmax, sp[w].rmax);
            r.cmin = min(r.cmin, sp[w].cmin);
            r.cmax = max(r.cmax, sp[w].cmax);
        }
        part[b * BPB + k] = Partial{r.cnt & 0xFFFF, r.cnt >> 16, r.pc, r.vc,
                                    r.rmin, r.rmax, r.cmin, r.cmax};
    }
}

__global__ __launch_bounds__(64)
void mfe_finalize(const Partial* __restrict__ part, float* __restrict__ out) {
    const int b    = blockIdx.x;
    const int lane = threadIdx.x;
    Partial r = part[b * BPB + lane];
    int pa = r.pa, va = r.va;
    float pc = r.pc, vc = r.vc;
    int rmin = r.rmin, rmax = r.rmax, cmin = r.cmin, cmax = r.cmax;

    #pragma unroll
    for (int off = 32; off > 0; off >>= 1) {
        pa += __shfl_down(pa, off, 64);
        va += __shfl_down(va, off, 64);
        pc += __shfl_down(pc, off, 64);
        vc += __shfl_down(vc, off, 64);
        rmin = min(rmin, __shfl_down(rmin, off, 64));
        rmax = max(rmax, __shfl_down(rmax, off, 64));
        cmin = min(cmin, __shfl_down(cmin, off, 64));
        cmax = max(cmax, __shfl_down(cmax, off, 64));
    }

    if (lane == 0) {
        const float paf = (float)pa;
        const float vaf = (float)va;
        const float fa  = paf + vaf;                  // fg = plaque + vessel
        const bool  ne  = (rmax >= 0);
        const float hr  = ne ? (float)(rmax - rmin) : 0.f;
        const float wr  = ne ? (float)(cmax - cmin) : 0.f;
        float* o = out + b * 10;
        o[0] = paf / (vaf + 1e-6f);
        o[1] = paf / (fa + 1e-6f);
        o[2] = pc;
        o[3] = hr / (float)HH;
        o[4] = wr / (float)WW;
        o[5] = 2.0f * (hr + wr) / (float)(HH + WW);
        o[6] = vc;
        o[7] = (pa > 0) ? (pc / (paf + 1e-6f)) : 0.f;
        o[8] = fa / (float)HWPIX;
        o[9] = paf / (float)HWPIX;
    }
}

extern "C" void kernel_launch(void* const* d_in, const int* in_sizes, int n_in,
                              void* d_out, int out_size, void* d_ws, size_t ws_size,
                              hipStream_t stream) {
    const float* in  = (const float*)d_in[0];
    float*       out = (float*)d_out;
    Partial*     part = (Partial*)d_ws;

    dim3 grid(BPB, NB);
    mfe_reduce<<<grid, NT, 0, stream>>>(in, part);
    mfe_finalize<<<NB, 64, 0, stream>>>(part, out);
}